// Round 1
// baseline (1421.821 us; speedup 1.0000x reference)
//
#include <hip/hip_runtime.h>
#include <cstdint>

#define BB 4
#define NN 2048
#define KK 32
#define CC 128
#define C0 128
#define C2 256
#define CIN0 259
#define EPSF 1e-5f
#define SLOPE 0.01f

// ---- workspace layout (float offsets) ----
// stats slots: sum[CL][32] then sumsq[CL][32] per layer
#define ST0 0            // 128*32*2 = 8192
#define ST1 8192         // 8192
#define ST2 16384        // 256*32*2 = 16384 -> ends 32768
#define PAR0 32768       // scale0[128], shift0[128]
#define PAR1 33024
#define PAR2 33280       // scale2[256], shift2[256] -> ends 33792
#define MAXOFF 34816
#define MINOFF (34816 + BB*NN*C2)   // + 2097152

__global__ __launch_bounds__(256) void zero_stats(float* ws) {
    int i = blockIdx.x * 256 + threadIdx.x;
    if (i < 32768) ws[i] = 0.f;
}

template<int OJ>
__device__ __forceinline__ void stats_accum(const float (&a)[4][OJ], int o0, int CL,
                                            int stoff, int slot, float* ws) {
#pragma unroll
    for (int j = 0; j < OJ; j++) {
        float s = 0.f, s2 = 0.f;
#pragma unroll
        for (int i = 0; i < 4; i++) { float v = a[i][j]; s += v; s2 += v * v; }
#pragma unroll
        for (int d = 1; d < 8; d <<= 1) { s += __shfl_xor(s, d); s2 += __shfl_xor(s2, d); }
        if ((threadIdx.x & 7) == 0) {
            atomicAdd(&ws[stoff + (o0 + j) * 32 + slot], s);
            atomicAdd(&ws[stoff + CL * 32 + (o0 + j) * 32 + slot], s2);
        }
    }
}

// One block = one (b,n). 256 threads: tx = t&7 -> k0 = 4*tx (4 of 32 neighbors),
// ty = t>>3 -> output-channel group. NL = how many layers this pass computes;
// stats are accumulated only for layer NL-1 (earlier layers use finalized params).
template<int NL>
__global__ __launch_bounds__(256, 2) void pass_kernel(
    const float* __restrict__ pos1, const float* __restrict__ pos2,
    const float* __restrict__ f1g, const float* __restrict__ f2g,
    const int* __restrict__ idx,
    const float* __restrict__ W0, const float* __restrict__ W1,
    const float* __restrict__ W2, float* __restrict__ ws)
{
    // Xs rows 0..127: gathered feature2 (W0 cols 3..130); rows 128..130: pos_diff (W0 cols 0..2)
    __shared__ __align__(16) float Xs[132][36];    // stride 36: b128-aligned, conflict-free
    __shared__ __align__(16) float Wts[32][264];   // W chunk transposed [cin][out], out<=256
    __shared__ float F1s[128];

    const int bid = blockIdx.x;
    const int b = bid >> 11, n = bid & (NN - 1);
    const int t = threadIdx.x;
    const int tx = t & 7, ty = t >> 3;
    const int k0 = tx * 4;
    const int slot = bid & 31;
    const int* idxp = idx + (size_t)bid * KK;

    // ---- stage gathered X ----
    {
        int k = t & 31, cg = t >> 5;               // 8 groups x 16 channels
        int j = idxp[k];
        const float* src = f2g + ((size_t)b * CC + cg * 16) * NN + j;
#pragma unroll
        for (int i = 0; i < 16; i++) Xs[cg * 16 + i][k] = src[(size_t)i * NN];
    }
    if (t < 96) {
        int k = t & 31, c = t >> 5;
        int j = idxp[k];
        Xs[128 + c][k] = pos2[((size_t)b * 3 + c) * NN + j] - pos1[((size_t)b * 3 + c) * NN + n];
    }
    if (t < 128) F1s[t] = f1g[((size_t)b * CC + t) * NN + n];

    float acc[4][4] = {};
    float sj[4] = {};

    // ---- layer 0: per-k feature2 part (W0 cols 3..130) ----
    for (int ch = 0; ch < 4; ch++) {
        __syncthreads();
        {
            int o = t & 127, h = t >> 7;
            const float* wp = W0 + (size_t)o * CIN0 + 3 + ch * 32 + h * 16;
#pragma unroll
            for (int i = 0; i < 16; i++) Wts[h * 16 + i][o] = wp[i];
        }
        __syncthreads();
#pragma unroll
        for (int cc = 0; cc < 32; cc++) {
            float4 xq = *(const float4*)&Xs[ch * 32 + cc][k0];
            float4 wq = *(const float4*)&Wts[cc][ty * 4];
            float xv[4] = {xq.x, xq.y, xq.z, xq.w};
            float wv[4] = {wq.x, wq.y, wq.z, wq.w};
#pragma unroll
            for (int i = 0; i < 4; i++)
#pragma unroll
                for (int j = 0; j < 4; j++) acc[i][j] = fmaf(xv[i], wv[j], acc[i][j]);
        }
    }
    // ---- layer 0: pos_diff part (W0 cols 0..2) ----
    __syncthreads();
    if (t < 128) {
        int o = t;
#pragma unroll
        for (int cc = 0; cc < 3; cc++) Wts[cc][o] = W0[(size_t)o * CIN0 + cc];
    }
    __syncthreads();
#pragma unroll
    for (int cc = 0; cc < 3; cc++) {
        float4 xq = *(const float4*)&Xs[128 + cc][k0];
        float4 wq = *(const float4*)&Wts[cc][ty * 4];
        float xv[4] = {xq.x, xq.y, xq.z, xq.w};
        float wv[4] = {wq.x, wq.y, wq.z, wq.w};
#pragma unroll
        for (int i = 0; i < 4; i++)
#pragma unroll
            for (int j = 0; j < 4; j++) acc[i][j] = fmaf(xv[i], wv[j], acc[i][j]);
    }
    // ---- layer 0: shared feature1 part (W0 cols 131..258), identical over k ----
    for (int ch = 0; ch < 4; ch++) {
        __syncthreads();
        {
            int o = t & 127, h = t >> 7;
            const float* wp = W0 + (size_t)o * CIN0 + 131 + ch * 32 + h * 16;
#pragma unroll
            for (int i = 0; i < 16; i++) Wts[h * 16 + i][o] = wp[i];
        }
        __syncthreads();
#pragma unroll
        for (int cc = 0; cc < 32; cc++) {
            float f1c = F1s[ch * 32 + cc];
            float4 wq = *(const float4*)&Wts[cc][ty * 4];
            float wv[4] = {wq.x, wq.y, wq.z, wq.w};
#pragma unroll
            for (int j = 0; j < 4; j++) sj[j] = fmaf(f1c, wv[j], sj[j]);
        }
    }
#pragma unroll
    for (int i = 0; i < 4; i++)
#pragma unroll
        for (int j = 0; j < 4; j++) acc[i][j] += sj[j];

    if constexpr (NL == 1) {
        stats_accum<4>(acc, ty * 4, C0, ST0, slot, ws);
        return;
    } else {
        // ---- BN0 + LeakyReLU, write h0 into Xs[c][k] ----
        __syncthreads();   // all Xs/Wts reads done before overwrite
#pragma unroll
        for (int j = 0; j < 4; j++) {
            float s = ws[PAR0 + ty * 4 + j], bsh = ws[PAR0 + C0 + ty * 4 + j];
            float hv[4];
#pragma unroll
            for (int i = 0; i < 4; i++) {
                float z = fmaf(acc[i][j], s, bsh);
                hv[i] = z >= 0.f ? z : SLOPE * z;
            }
            *(float4*)&Xs[ty * 4 + j][k0] = *(float4*)hv;
        }

        // ---- layer 1 ----
        float acc1[4][4] = {};
        for (int ch = 0; ch < 4; ch++) {
            __syncthreads();
            {
                int o = t & 127, h = t >> 7;
                const float* wp = W1 + (size_t)o * C0 + ch * 32 + h * 16;
#pragma unroll
                for (int i = 0; i < 16; i++) Wts[h * 16 + i][o] = wp[i];
            }
            __syncthreads();
#pragma unroll
            for (int cc = 0; cc < 32; cc++) {
                float4 xq = *(const float4*)&Xs[ch * 32 + cc][k0];
                float4 wq = *(const float4*)&Wts[cc][ty * 4];
                float xv[4] = {xq.x, xq.y, xq.z, xq.w};
                float wv[4] = {wq.x, wq.y, wq.z, wq.w};
#pragma unroll
                for (int i = 0; i < 4; i++)
#pragma unroll
                    for (int j = 0; j < 4; j++) acc1[i][j] = fmaf(xv[i], wv[j], acc1[i][j]);
            }
        }

        if constexpr (NL == 2) {
            stats_accum<4>(acc1, ty * 4, C0, ST1, slot, ws);
            return;
        } else {
            // ---- BN1 + LeakyReLU, write h1 into Xs ----
            __syncthreads();
#pragma unroll
            for (int j = 0; j < 4; j++) {
                float s = ws[PAR1 + ty * 4 + j], bsh = ws[PAR1 + C0 + ty * 4 + j];
                float hv[4];
#pragma unroll
                for (int i = 0; i < 4; i++) {
                    float z = fmaf(acc1[i][j], s, bsh);
                    hv[i] = z >= 0.f ? z : SLOPE * z;
                }
                *(float4*)&Xs[ty * 4 + j][k0] = *(float4*)hv;
            }

            // ---- layer 2 (256 outs: 8 per thread) ----
            float acc2[4][8] = {};
            for (int ch = 0; ch < 4; ch++) {
                __syncthreads();
                {
                    int o = t;
                    const float* wp = W2 + (size_t)o * C0 + ch * 32;
#pragma unroll
                    for (int i = 0; i < 32; i++) Wts[i][o] = wp[i];
                }
                __syncthreads();
#pragma unroll
                for (int cc = 0; cc < 32; cc++) {
                    float4 xq = *(const float4*)&Xs[ch * 32 + cc][k0];
                    float4 wqa = *(const float4*)&Wts[cc][ty * 8];
                    float4 wqb = *(const float4*)&Wts[cc][ty * 8 + 4];
                    float xv[4] = {xq.x, xq.y, xq.z, xq.w};
                    float wv[8] = {wqa.x, wqa.y, wqa.z, wqa.w, wqb.x, wqb.y, wqb.z, wqb.w};
#pragma unroll
                    for (int i = 0; i < 4; i++)
#pragma unroll
                        for (int j = 0; j < 8; j++) acc2[i][j] = fmaf(xv[i], wv[j], acc2[i][j]);
                }
            }
            // ---- stats + per-(b,n,c) max/min over K of raw y2 ----
            stats_accum<8>(acc2, ty * 8, C2, ST2, slot, ws);
#pragma unroll
            for (int j = 0; j < 8; j++) {
                float mx = -1e30f, mn = 1e30f;
#pragma unroll
                for (int i = 0; i < 4; i++) { mx = fmaxf(mx, acc2[i][j]); mn = fminf(mn, acc2[i][j]); }
#pragma unroll
                for (int d = 1; d < 8; d <<= 1) {
                    mx = fmaxf(mx, __shfl_xor(mx, d));
                    mn = fminf(mn, __shfl_xor(mn, d));
                }
                if (tx == 0) {
                    ws[MAXOFF + (size_t)bid * C2 + ty * 8 + j] = mx;
                    ws[MINOFF + (size_t)bid * C2 + ty * 8 + j] = mn;
                }
            }
        }
    }
}

__global__ void finalize(const float* __restrict__ g, const float* __restrict__ bparm,
                         float* __restrict__ ws, int CL, int stoff, int paroff) {
    int o = threadIdx.x;
    if (o >= CL) return;
    float s = 0.f, s2 = 0.f;
    for (int i = 0; i < 32; i++) {
        s  += ws[stoff + o * 32 + i];
        s2 += ws[stoff + CL * 32 + o * 32 + i];
    }
    const float inv = 1.0f / ((float)BB * NN * KK);
    float mean = s * inv, var = s2 * inv - mean * mean;
    float sc = g[o] * rsqrtf(var + EPSF);
    ws[paroff + o] = sc;
    ws[paroff + CL + o] = bparm[o] - mean * sc;
}

// max-pool commutes with monotone affine+lrelu: out = lrelu(scale*(scale>=0?max:min)+shift)
// Reads M[b][n][o] coalesced, transposes through LDS, writes out[b][o][n] coalesced.
__global__ __launch_bounds__(256) void out_kernel(const float* __restrict__ ws,
                                                  float* __restrict__ out) {
    __shared__ float T[32][261];
    int blk = blockIdx.x;                  // BB * (NN/32) = 256 blocks
    int b = blk >> 6, n0 = (blk & 63) * 32;
    int t = threadIdx.x;
    float s = ws[PAR2 + t], sh = ws[PAR2 + C2 + t];
    const float* Mx = ws + MAXOFF;
    const float* Mn = ws + MINOFF;
    for (int r = 0; r < 32; r++) {
        size_t base = ((size_t)(b * NN + n0 + r)) * C2 + t;
        float v = (s >= 0.f) ? Mx[base] : Mn[base];
        float z = fmaf(v, s, sh);
        T[r][t] = z >= 0.f ? z : SLOPE * z;
    }
    __syncthreads();
    float* o2 = out + BB * 3 * NN;
    int c = t & 31, og = t >> 5;
    for (int ss = 0; ss < 32; ss++) {
        int o = og * 32 + ss;
        o2[((size_t)(b * C2 + o)) * NN + n0 + c] = T[c][o];
    }
}

extern "C" void kernel_launch(void* const* d_in, const int* in_sizes, int n_in,
                              void* d_out, int out_size, void* d_ws, size_t ws_size,
                              hipStream_t stream) {
    const float* pos1 = (const float*)d_in[0];
    const float* pos2 = (const float*)d_in[1];
    const float* f1   = (const float*)d_in[2];
    const float* f2   = (const float*)d_in[3];
    const int*   idx  = (const int*)d_in[4];
    const float* W0 = (const float*)d_in[5];
    const float* g0 = (const float*)d_in[6];
    const float* b0 = (const float*)d_in[7];
    const float* W1 = (const float*)d_in[8];
    const float* g1 = (const float*)d_in[9];
    const float* b1 = (const float*)d_in[10];
    const float* W2 = (const float*)d_in[11];
    const float* g2 = (const float*)d_in[12];
    const float* b2 = (const float*)d_in[13];
    float* ws  = (float*)d_ws;
    float* out = (float*)d_out;

    // output 0: pos1 passthrough
    hipMemcpyAsync(d_out, d_in[0], (size_t)BB * 3 * NN * sizeof(float),
                   hipMemcpyDeviceToDevice, stream);

    zero_stats<<<128, 256, 0, stream>>>(ws);

    pass_kernel<1><<<BB * NN, 256, 0, stream>>>(pos1, pos2, f1, f2, idx, W0, W1, W2, ws);
    finalize<<<1, 256, 0, stream>>>(g0, b0, ws, C0, ST0, PAR0);

    pass_kernel<2><<<BB * NN, 256, 0, stream>>>(pos1, pos2, f1, f2, idx, W0, W1, W2, ws);
    finalize<<<1, 256, 0, stream>>>(g1, b1, ws, C0, ST1, PAR1);

    pass_kernel<3><<<BB * NN, 256, 0, stream>>>(pos1, pos2, f1, f2, idx, W0, W1, W2, ws);
    finalize<<<1, 256, 0, stream>>>(g2, b2, ws, C2, ST2, PAR2);

    out_kernel<<<BB * (NN / 32), 256, 0, stream>>>(ws, out);
}

// Round 2
// 584.599 us; speedup vs baseline: 2.4321x; 2.4321x over previous
//
#include <hip/hip_runtime.h>
#include <cstdint>

#define BB 4
#define NN 2048
#define KK 32
#define CC 128
#define C0 128
#define C2 256
#define CIN0 259
#define EPSF 1e-5f
#define SLOPE 0.01f

// ---- workspace layout (float offsets) ----
#define ST0 0            // 128*32*2
#define ST1 8192
#define ST2 16384        // -> 32768
#define PAR0 32768
#define PAR1 33024
#define PAR2 33280       // -> 33792
#define MAXOFF 34816
#define MINOFF (34816 + BB*NN*C2)
#define WPOFF  (34816 + 2*BB*NN*C2)   // = 4229120 floats; bf16 packed W after this

// packed-W frag counts: L0: 8 mt x 9 ck = 72; L1: 8x4=32; L2: 16x4=64 (512 bf16 each)
#define NFRAG0 72
#define NFRAG1 32
#define NFRAG2 64

typedef float  floatx4 __attribute__((ext_vector_type(4)));
typedef short  shortx8 __attribute__((ext_vector_type(8)));

#define MFMA16(A,B,C) __builtin_amdgcn_mfma_f32_16x16x32_bf16((A),(B),(C),0,0,0)

__device__ __forceinline__ ushort f2bf(float f) {
    union { float f; uint u; } v; v.f = f;
    uint r = (v.u + 0x7fffu + ((v.u >> 16) & 1u)) >> 16;
    return (ushort)r;
}

__global__ __launch_bounds__(256) void zero_stats(float* ws) {
    int i = blockIdx.x * 256 + threadIdx.x;
    if (i < 32768) ws[i] = 0.f;
}

// Pack W0/W1/W2 (f32, row-major [o][cin]) into bf16 MFMA A-fragment order.
// A-frag lane l of tile (mt,ck): W[mt*16 + (l&15)][ck*32 + (l>>4)*8 + i], i=0..7.
// cin order for L0 (matches X staging): 0-127 f2g(ch c -> W0 col 3+c),
// 128-130 posdiff(-> col c-128), 131-159 zero pad, 160-287 f1(-> col c-29).
__global__ __launch_bounds__(256) void pack_w(const float* __restrict__ W0,
                                              const float* __restrict__ W1,
                                              const float* __restrict__ W2,
                                              short* __restrict__ wp0) {
    int tid = blockIdx.x * 256 + threadIdx.x;   // 168*64 = 10752 threads
    int fid = tid >> 6, lane = tid & 63, g = lane >> 4, lcol = lane & 15;
    short* wp1 = wp0 + NFRAG0 * 512;
    short* wp2 = wp1 + NFRAG1 * 512;
    ushort v[8];
    short* dst;
    if (fid < NFRAG0) {
        int mt = fid / 9, ck = fid % 9, o = mt * 16 + lcol;
        const float* wrow = W0 + (size_t)o * CIN0;
#pragma unroll
        for (int i = 0; i < 8; i++) {
            int c = ck * 32 + g * 8 + i;
            float x;
            if (c < 128)       x = wrow[3 + c];
            else if (c < 131)  x = wrow[c - 128];
            else if (c < 160)  x = 0.f;
            else               x = wrow[c - 29];
            v[i] = f2bf(x);
        }
        dst = wp0 + ((size_t)fid * 64 + lane) * 8;
    } else if (fid < NFRAG0 + NFRAG1) {
        int f = fid - NFRAG0, mt = f / 4, ck = f % 4, o = mt * 16 + lcol;
#pragma unroll
        for (int i = 0; i < 8; i++) v[i] = f2bf(W1[(size_t)o * C0 + ck * 32 + g * 8 + i]);
        dst = wp1 + ((size_t)f * 64 + lane) * 8;
    } else {
        int f = fid - NFRAG0 - NFRAG1, mt = f / 4, ck = f % 4, o = mt * 16 + lcol;
#pragma unroll
        for (int i = 0; i < 8; i++) v[i] = f2bf(W2[(size_t)o * C0 + ck * 32 + g * 8 + i]);
        dst = wp2 + ((size_t)f * 64 + lane) * 8;
    }
#pragma unroll
    for (int i = 0; i < 8; i++) dst[i] = (short)v[i];
}

// stats reduce: acc[m][nt][r] holds y for ch=(mtbase+m)*16+g*4+r, k=nt*16+lcol.
template<int NM>
__device__ __forceinline__ void mfma_stats(const floatx4 (&acc)[NM][2], int mtbase,
                                           int g, int lcol, int CL, int stoff,
                                           int slot, float* ws) {
#pragma unroll
    for (int m = 0; m < NM; m++) {
#pragma unroll
        for (int r = 0; r < 4; r++) {
            float a0 = acc[m][0][r], a1 = acc[m][1][r];
            float s = a0 + a1, s2 = a0 * a0 + a1 * a1;
#pragma unroll
            for (int d = 1; d < 16; d <<= 1) { s += __shfl_xor(s, d); s2 += __shfl_xor(s2, d); }
            if (lcol == 0) {
                int ch = (mtbase + m) * 16 + g * 4 + r;
                atomicAdd(&ws[stoff + ch * 32 + slot], s);
                atomicAdd(&ws[stoff + CL * 32 + ch * 32 + slot], s2);
            }
        }
    }
}

// BN+lrelu on acc, store bf16 into Xd[k][ch] (pitch P)
template<int NM, int P>
__device__ __forceinline__ void bn_store(const floatx4 (&acc)[NM][2], int mtbase,
                                         int g, int lcol, int paroff,
                                         const float* __restrict__ ws, ushort (*Xd)[P]) {
#pragma unroll
    for (int m = 0; m < NM; m++) {
        int ch = (mtbase + m) * 16 + g * 4;
        floatx4 sc = *(const floatx4*)&ws[paroff + ch];
        floatx4 sh = *(const floatx4*)&ws[paroff + C0 + ch];
#pragma unroll
        for (int nt = 0; nt < 2; nt++) {
            ushort h[4];
#pragma unroll
            for (int r = 0; r < 4; r++) {
                float z = fmaf(acc[m][nt][r], sc[r], sh[r]);
                z = z >= 0.f ? z : SLOPE * z;
                h[r] = f2bf(z);
            }
            uint2 val;
            val.x = (uint)h[0] | ((uint)h[1] << 16);
            val.y = (uint)h[2] | ((uint)h[3] << 16);
            *(uint2*)&Xd[nt * 16 + lcol][ch] = val;
        }
    }
}

// One block = one (b,n); 4 waves. NL = layers computed this pass; stats for layer NL-1.
template<int NL>
__global__ __launch_bounds__(256, 4) void pass_kernel(
    const float* __restrict__ pos1, const float* __restrict__ pos2,
    const float* __restrict__ f1g, const float* __restrict__ f2g,
    const int* __restrict__ idx,
    const short* __restrict__ wp0, float* __restrict__ ws)
{
    // X0[k][cin]: cols 0-127 f2g, 128-130 posdiff, 131-159 zero (chunk 4 pad)
    __shared__ __align__(16) ushort X0[32][168];
    __shared__ __align__(16) ushort X1[32][136];
    __shared__ __align__(16) ushort F1s[128];

    const int bid = blockIdx.x;
    const int b = bid >> 11, n = bid & (NN - 1);
    const int t = threadIdx.x;
    const int wave = t >> 6, lane = t & 63, g = lane >> 4, lcol = lane & 15;
    const int slot = bid & 31;
    const int* idxp = idx + (size_t)bid * KK;
    const shortx8* wf0 = (const shortx8*)wp0;
    const shortx8* wf1 = wf0 + NFRAG0 * 64;
    const shortx8* wf2 = wf1 + NFRAG1 * 64;

    // ---- stage gathered X (transposed [k][cin], bf16) ----
    {
        int k = t & 31, cg = t >> 5;               // 8 groups x 16 channels
        int j = idxp[k];
        const float* src = f2g + ((size_t)b * CC + cg * 16) * NN + j;
        uint* dst = (uint*)&X0[k][cg * 16];
#pragma unroll
        for (int i = 0; i < 8; i++) {
            float v0 = src[(size_t)(2 * i) * NN], v1 = src[(size_t)(2 * i + 1) * NN];
            dst[i] = (uint)f2bf(v0) | ((uint)f2bf(v1) << 16);
        }
    }
    if (t < 32) {
        int k = t, j = idxp[k];
#pragma unroll
        for (int c = 0; c < 3; c++)
            X0[k][128 + c] = f2bf(pos2[((size_t)b * 3 + c) * NN + j] -
                                  pos1[((size_t)b * 3 + c) * NN + n]);
        for (int c = 131; c < 168; c++) X0[k][c] = 0;
    }
    if (t < 128) F1s[t] = f2bf(f1g[((size_t)b * CC + t) * NN + n]);
    __syncthreads();

    // ---- layer 0: 9 cin-chunks (0-4 from X0, 5-8 broadcast from F1s) ----
    floatx4 acc0[2][2] = {};
#pragma unroll
    for (int ck = 0; ck < 9; ck++) {
        shortx8 B0, B1;
        if (ck < 5) {
            B0 = *(const shortx8*)&X0[lcol][ck * 32 + g * 8];
            B1 = *(const shortx8*)&X0[lcol + 16][ck * 32 + g * 8];
        } else {
            shortx8 F = *(const shortx8*)&F1s[(ck - 5) * 32 + g * 8];
            B0 = F; B1 = F;
        }
#pragma unroll
        for (int m = 0; m < 2; m++) {
            shortx8 A = wf0[((wave * 2 + m) * 9 + ck) * 64 + lane];
            acc0[m][0] = MFMA16(A, B0, acc0[m][0]);
            acc0[m][1] = MFMA16(A, B1, acc0[m][1]);
        }
    }

    if constexpr (NL == 1) {
        mfma_stats<2>(acc0, wave * 2, g, lcol, C0, ST0, slot, ws);
        return;
    } else {
        bn_store<2, 136>(acc0, wave * 2, g, lcol, PAR0, ws, X1);
        __syncthreads();

        // ---- layer 1 ----
        floatx4 acc1[2][2] = {};
#pragma unroll
        for (int ck = 0; ck < 4; ck++) {
            shortx8 B0 = *(const shortx8*)&X1[lcol][ck * 32 + g * 8];
            shortx8 B1 = *(const shortx8*)&X1[lcol + 16][ck * 32 + g * 8];
#pragma unroll
            for (int m = 0; m < 2; m++) {
                shortx8 A = wf1[((wave * 2 + m) * 4 + ck) * 64 + lane];
                acc1[m][0] = MFMA16(A, B0, acc1[m][0]);
                acc1[m][1] = MFMA16(A, B1, acc1[m][1]);
            }
        }

        if constexpr (NL == 2) {
            mfma_stats<2>(acc1, wave * 2, g, lcol, C0, ST1, slot, ws);
            return;
        } else {
            bn_store<2, 168>(acc1, wave * 2, g, lcol, PAR1, ws, X0);  // h1 reuses X0
            __syncthreads();

            // ---- layer 2 (M=256: 4 M-tiles per wave) ----
            floatx4 acc2[4][2] = {};
#pragma unroll
            for (int ck = 0; ck < 4; ck++) {
                shortx8 B0 = *(const shortx8*)&X0[lcol][ck * 32 + g * 8];
                shortx8 B1 = *(const shortx8*)&X0[lcol + 16][ck * 32 + g * 8];
#pragma unroll
                for (int m = 0; m < 4; m++) {
                    shortx8 A = wf2[((wave * 4 + m) * 4 + ck) * 64 + lane];
                    acc2[m][0] = MFMA16(A, B0, acc2[m][0]);
                    acc2[m][1] = MFMA16(A, B1, acc2[m][1]);
                }
            }

            mfma_stats<4>(acc2, wave * 4, g, lcol, C2, ST2, slot, ws);

            // per-(b,n,ch) max/min over k (reduce the 2 N-tiles then 16 lanes)
#pragma unroll
            for (int m = 0; m < 4; m++) {
                floatx4 mx, mn;
#pragma unroll
                for (int r = 0; r < 4; r++) {
                    mx[r] = fmaxf(acc2[m][0][r], acc2[m][1][r]);
                    mn[r] = fminf(acc2[m][0][r], acc2[m][1][r]);
                }
#pragma unroll
                for (int d = 1; d < 16; d <<= 1) {
#pragma unroll
                    for (int r = 0; r < 4; r++) {
                        mx[r] = fmaxf(mx[r], __shfl_xor(mx[r], d));
                        mn[r] = fminf(mn[r], __shfl_xor(mn[r], d));
                    }
                }
                if (lcol == 0) {
                    int ch = (wave * 4 + m) * 16 + g * 4;
                    *(floatx4*)&ws[MAXOFF + (size_t)bid * C2 + ch] = mx;
                    *(floatx4*)&ws[MINOFF + (size_t)bid * C2 + ch] = mn;
                }
            }
        }
    }
}

__global__ void finalize(const float* __restrict__ g, const float* __restrict__ bparm,
                         float* __restrict__ ws, int CL, int stoff, int paroff) {
    int o = threadIdx.x;
    if (o >= CL) return;
    float s = 0.f, s2 = 0.f;
    for (int i = 0; i < 32; i++) {
        s  += ws[stoff + o * 32 + i];
        s2 += ws[stoff + CL * 32 + o * 32 + i];
    }
    const float inv = 1.0f / ((float)BB * NN * KK);
    float mean = s * inv, var = s2 * inv - mean * mean;
    float sc = g[o] * rsqrtf(var + EPSF);
    ws[paroff + o] = sc;
    ws[paroff + CL + o] = bparm[o] - mean * sc;
}

// max-pool commutes with monotone affine+lrelu: out = lrelu(scale*(scale>=0?max:min)+shift)
__global__ __launch_bounds__(256) void out_kernel(const float* __restrict__ ws,
                                                  float* __restrict__ out) {
    __shared__ float T[32][261];
    int blk = blockIdx.x;                  // BB * (NN/32) = 256 blocks
    int b = blk >> 6, n0 = (blk & 63) * 32;
    int t = threadIdx.x;
    float s = ws[PAR2 + t], sh = ws[PAR2 + C2 + t];
    const float* Mx = ws + MAXOFF;
    const float* Mn = ws + MINOFF;
    for (int r = 0; r < 32; r++) {
        size_t base = ((size_t)(b * NN + n0 + r)) * C2 + t;
        float v = (s >= 0.f) ? Mx[base] : Mn[base];
        float z = fmaf(v, s, sh);
        T[r][t] = z >= 0.f ? z : SLOPE * z;
    }
    __syncthreads();
    float* o2 = out + BB * 3 * NN;
    int c = t & 31, og = t >> 5;
    for (int ss = 0; ss < 32; ss++) {
        int o = og * 32 + ss;
        o2[((size_t)(b * C2 + o)) * NN + n0 + c] = T[c][o];
    }
}

extern "C" void kernel_launch(void* const* d_in, const int* in_sizes, int n_in,
                              void* d_out, int out_size, void* d_ws, size_t ws_size,
                              hipStream_t stream) {
    const float* pos1 = (const float*)d_in[0];
    const float* pos2 = (const float*)d_in[1];
    const float* f1   = (const float*)d_in[2];
    const float* f2   = (const float*)d_in[3];
    const int*   idx  = (const int*)d_in[4];
    const float* W0 = (const float*)d_in[5];
    const float* g0 = (const float*)d_in[6];
    const float* b0 = (const float*)d_in[7];
    const float* W1 = (const float*)d_in[8];
    const float* g1 = (const float*)d_in[9];
    const float* b1 = (const float*)d_in[10];
    const float* W2 = (const float*)d_in[11];
    const float* g2 = (const float*)d_in[12];
    const float* b2 = (const float*)d_in[13];
    float* ws  = (float*)d_ws;
    float* out = (float*)d_out;
    short* wp0 = (short*)(ws + WPOFF);

    // output 0: pos1 passthrough
    hipMemcpyAsync(d_out, d_in[0], (size_t)BB * 3 * NN * sizeof(float),
                   hipMemcpyDeviceToDevice, stream);

    zero_stats<<<128, 256, 0, stream>>>(ws);
    pack_w<<<(NFRAG0 + NFRAG1 + NFRAG2) * 64 / 256, 256, 0, stream>>>(W0, W1, W2, wp0);

    pass_kernel<1><<<BB * NN, 256, 0, stream>>>(pos1, pos2, f1, f2, idx, wp0, ws);
    finalize<<<1, 256, 0, stream>>>(g0, b0, ws, C0, ST0, PAR0);

    pass_kernel<2><<<BB * NN, 256, 0, stream>>>(pos1, pos2, f1, f2, idx, wp0, ws);
    finalize<<<1, 256, 0, stream>>>(g1, b1, ws, C0, ST1, PAR1);

    pass_kernel<3><<<BB * NN, 256, 0, stream>>>(pos1, pos2, f1, f2, idx, wp0, ws);
    finalize<<<1, 256, 0, stream>>>(g2, b2, ws, C2, ST2, PAR2);

    out_kernel<<<BB * (NN / 32), 256, 0, stream>>>(ws, out);
}

// Round 3
// 433.507 us; speedup vs baseline: 3.2798x; 1.3485x over previous
//
#include <hip/hip_runtime.h>
#include <cstdint>

#define BB 4
#define NN 2048
#define KK 32
#define CC 128
#define C0 128
#define C2 256
#define CIN0 259
#define EPSF 1e-5f
#define SLOPE 0.01f

// ---- ws layout (float offsets unless noted) ----
#define PAR0 0                            // scale128|shift128
#define PAR1 256
#define PAR2 512                          // scale256|shift256 -> end 1024
#define R1OFF 1024                        // 64*512 reduce1 output -> end 33792
#define MAXOFF 33792                      // 2M floats; ALSO partial rows (8192x512) for pass1/2
#define MINOFF (MAXOFF + 2097152)
#define PART3 (MAXOFF + 4194304)          // 4228096: 4096x512 partials for pass3
#define PART3_END (PART3 + 2097152)       // 6325248
#define T2_USH (PART3_END * 2)            // ushort offset 12650496, 1048576 ush
#define T1_USH (T2_USH + 1048576)         // + 1048576 -> end ush 14747648 (= float 7373824)
#define P1TOFF 7373824                    // 32768 floats
#define P2TOFF (P1TOFF + 32768)           // -> end 7439360
#define WP_USH 14878720                   // packed W, 86016 ush -> total ~29.9 MB

#define NFRAG0 72
#define NFRAG1 32
#define NFRAG2 64

typedef float floatx4 __attribute__((ext_vector_type(4)));
typedef short shortx8 __attribute__((ext_vector_type(8)));

#define MFMA16(A,B,C) __builtin_amdgcn_mfma_f32_16x16x32_bf16((A),(B),(C),0,0,0)

__device__ __forceinline__ ushort f2bf(float f) {
    union { float f; uint u; } v; v.f = f;
    uint r = (v.u + 0x7fffu + ((v.u >> 16) & 1u)) >> 16;
    return (ushort)r;
}

// [b][C][N] f32 -> [b][N][C] bf16
__global__ __launch_bounds__(256) void transpose_cn(const float* __restrict__ src,
                                                    ushort* __restrict__ dst) {
    __shared__ ushort Ts[32][136];
    int b = blockIdx.x >> 6, n0 = (blockIdx.x & 63) * 32;
    int t = threadIdx.x;
#pragma unroll
    for (int i = 0; i < 16; i++) {
        int c = i * 8 + (t >> 5);
        Ts[t & 31][c] = f2bf(src[((size_t)b * CC + c) * NN + n0 + (t & 31)]);
    }
    __syncthreads();
    int n = t >> 3, c0 = (t & 7) * 16;
    ushort* drow = dst + ((size_t)b * NN + n0 + n) * CC + c0;
    *(uint4*)drow = *(const uint4*)&Ts[n][c0];
    *(uint4*)(drow + 8) = *(const uint4*)&Ts[n][c0 + 8];
}

// pos[b][3][N] f32 -> [b][N][4] f32
__global__ __launch_bounds__(256) void transpose_pos(const float* __restrict__ p1,
                                                     const float* __restrict__ p2,
                                                     float* __restrict__ d1,
                                                     float* __restrict__ d2) {
    int i = blockIdx.x * 256 + threadIdx.x;       // 8192
    int b = i >> 11, n = i & (NN - 1);
    float4 v1, v2;
    v1.x = p1[((size_t)b * 3 + 0) * NN + n];
    v1.y = p1[((size_t)b * 3 + 1) * NN + n];
    v1.z = p1[((size_t)b * 3 + 2) * NN + n];
    v1.w = 0.f;
    v2.x = p2[((size_t)b * 3 + 0) * NN + n];
    v2.y = p2[((size_t)b * 3 + 1) * NN + n];
    v2.z = p2[((size_t)b * 3 + 2) * NN + n];
    v2.w = 0.f;
    *(float4*)&d1[(size_t)i * 4] = v1;
    *(float4*)&d2[(size_t)i * 4] = v2;
}

// Pack W0/W1/W2 into bf16 MFMA A-fragment order.
// cin order L0: 0-127 f2g(W0 col 3+c), 128-130 posdiff(col c-128), 131-159 zero, 160-287 f1(col c-29)
__global__ __launch_bounds__(256) void pack_w(const float* __restrict__ W0,
                                              const float* __restrict__ W1,
                                              const float* __restrict__ W2,
                                              short* __restrict__ wp0) {
    int tid = blockIdx.x * 256 + threadIdx.x;   // 168*64 = 10752
    int fid = tid >> 6, lane = tid & 63, g = lane >> 4, lcol = lane & 15;
    short* wp1 = wp0 + NFRAG0 * 512;
    short* wp2 = wp1 + NFRAG1 * 512;
    ushort v[8];
    short* dst;
    if (fid < NFRAG0) {
        int mt = fid / 9, ck = fid % 9, o = mt * 16 + lcol;
        const float* wrow = W0 + (size_t)o * CIN0;
#pragma unroll
        for (int i = 0; i < 8; i++) {
            int c = ck * 32 + g * 8 + i;
            float x;
            if (c < 128)       x = wrow[3 + c];
            else if (c < 131)  x = wrow[c - 128];
            else if (c < 160)  x = 0.f;
            else               x = wrow[c - 29];
            v[i] = f2bf(x);
        }
        dst = wp0 + ((size_t)fid * 64 + lane) * 8;
    } else if (fid < NFRAG0 + NFRAG1) {
        int f = fid - NFRAG0, mt = f / 4, ck = f % 4, o = mt * 16 + lcol;
#pragma unroll
        for (int i = 0; i < 8; i++) v[i] = f2bf(W1[(size_t)o * C0 + ck * 32 + g * 8 + i]);
        dst = wp1 + ((size_t)f * 64 + lane) * 8;
    } else {
        int f = fid - NFRAG0 - NFRAG1, mt = f / 4, ck = f % 4, o = mt * 16 + lcol;
#pragma unroll
        for (int i = 0; i < 8; i++) v[i] = f2bf(W2[(size_t)o * C0 + ck * 32 + g * 8 + i]);
        dst = wp2 + ((size_t)f * 64 + lane) * 8;
    }
#pragma unroll
    for (int i = 0; i < 8; i++) dst[i] = (short)v[i];
}

// per-point stats row store for 128-channel layers (layout [sum128|sq128], pitch 512)
__device__ __forceinline__ void store_stats128(const floatx4 (&acc)[2][2], int wave, int g,
                                               int lcol, int pid, float* ws) {
#pragma unroll
    for (int m = 0; m < 2; m++) {
        floatx4 s, s2;
#pragma unroll
        for (int r = 0; r < 4; r++) {
            float a0 = acc[m][0][r], a1 = acc[m][1][r];
            float ss = a0 + a1, qq = a0 * a0 + a1 * a1;
#pragma unroll
            for (int d = 1; d < 16; d <<= 1) { ss += __shfl_xor(ss, d); qq += __shfl_xor(qq, d); }
            s[r] = ss; s2[r] = qq;
        }
        if (lcol == 0) {
            int ch = wave * 32 + m * 16 + g * 4;
            *(floatx4*)&ws[MAXOFF + (size_t)pid * 512 + ch] = s;
            *(floatx4*)&ws[MAXOFF + (size_t)pid * 512 + 128 + ch] = s2;
        }
    }
}

// BN+lrelu C-layout acc -> bf16 into H[k][ch]
__device__ __forceinline__ void bn_to_H(const floatx4 (&acc)[2][2], int wave, int g, int lcol,
                                        int paroff, const float* __restrict__ ws,
                                        ushort (*H)[136]) {
#pragma unroll
    for (int m = 0; m < 2; m++) {
        int ch = wave * 32 + m * 16 + g * 4;
        floatx4 sc = *(const floatx4*)&ws[paroff + ch];
        floatx4 sh = *(const floatx4*)&ws[paroff + 128 + ch];
#pragma unroll
        for (int nt = 0; nt < 2; nt++) {
            ushort h[4];
#pragma unroll
            for (int r = 0; r < 4; r++) {
                float z = fmaf(acc[m][nt][r], sc[r], sh[r]);
                z = z >= 0.f ? z : SLOPE * z;
                h[r] = f2bf(z);
            }
            uint2 val;
            val.x = (uint)h[0] | ((uint)h[1] << 16);
            val.y = (uint)h[2] | ((uint)h[3] << 16);
            *(uint2*)&H[nt * 16 + lcol][ch] = val;
        }
    }
}

// One block = 2 points (pid = bid*2+p); 4 waves; B-frags direct from global, no atomics.
template<int NL>
__global__ __launch_bounds__(256, 2) void pass_kernel(
    const ushort* __restrict__ T2g, const ushort* __restrict__ T1g,
    const float* __restrict__ P1T, const float* __restrict__ P2T,
    const int* __restrict__ idxg, const short* __restrict__ wp0,
    float* __restrict__ ws)
{
    __shared__ __align__(16) ushort H[32][136];
    const int bid = blockIdx.x;
    const int t = threadIdx.x;
    const int wave = t >> 6, lane = t & 63, g = lane >> 4, lcol = lane & 15;
    const shortx8* wf0 = (const shortx8*)wp0;
    const shortx8* wf1 = wf0 + NFRAG0 * 64;
    const shortx8* wf2 = wf1 + NFRAG1 * 64;

    floatx4 sv[4] = {}, s2v[4] = {};    // NL3 stats accumulated over both points

    for (int p = 0; p < 2; ++p) {
        const int pid = bid * 2 + p;
        const int b = pid >> 11, n = pid & (NN - 1);
        const int j0 = idxg[pid * KK + lcol];
        const int j1 = idxg[pid * KK + 16 + lcol];
        const ushort* r0 = T2g + ((size_t)(b * NN + j0)) * CC;
        const ushort* r1 = T2g + ((size_t)(b * NN + j1)) * CC;
        const ushort* f1r = T1g + ((size_t)(b * NN + n)) * CC;

        // ---- layer 0 ----
        floatx4 acc0[2][2] = {};
#pragma unroll
        for (int ck = 0; ck < 4; ck++) {            // f2 chunks
            shortx8 B0 = *(const shortx8*)(r0 + ck * 32 + g * 8);
            shortx8 B1 = *(const shortx8*)(r1 + ck * 32 + g * 8);
#pragma unroll
            for (int m = 0; m < 2; m++) {
                shortx8 A = wf0[((wave * 2 + m) * 9 + ck) * 64 + lane];
                acc0[m][0] = MFMA16(A, B0, acc0[m][0]);
                acc0[m][1] = MFMA16(A, B1, acc0[m][1]);
            }
        }
        {                                           // posdiff chunk (ck=4)
            shortx8 B0, B1;
#pragma unroll
            for (int i = 0; i < 8; i++) { B0[i] = 0; B1[i] = 0; }
            if (g == 0) {
                floatx4 q0 = *(const floatx4*)(P2T + (size_t)(b * NN + j0) * 4);
                floatx4 q1 = *(const floatx4*)(P2T + (size_t)(b * NN + j1) * 4);
                floatx4 qc = *(const floatx4*)(P1T + (size_t)(b * NN + n) * 4);
#pragma unroll
                for (int c = 0; c < 3; c++) {
                    B0[c] = (short)f2bf(q0[c] - qc[c]);
                    B1[c] = (short)f2bf(q1[c] - qc[c]);
                }
            }
#pragma unroll
            for (int m = 0; m < 2; m++) {
                shortx8 A = wf0[((wave * 2 + m) * 9 + 4) * 64 + lane];
                acc0[m][0] = MFMA16(A, B0, acc0[m][0]);
                acc0[m][1] = MFMA16(A, B1, acc0[m][1]);
            }
        }
#pragma unroll
        for (int ck = 5; ck < 9; ck++) {            // f1 chunks (k-broadcast)
            shortx8 F = *(const shortx8*)(f1r + (ck - 5) * 32 + g * 8);
#pragma unroll
            for (int m = 0; m < 2; m++) {
                shortx8 A = wf0[((wave * 2 + m) * 9 + ck) * 64 + lane];
                acc0[m][0] = MFMA16(A, F, acc0[m][0]);
                acc0[m][1] = MFMA16(A, F, acc0[m][1]);
            }
        }

        if constexpr (NL == 1) {
            store_stats128(acc0, wave, g, lcol, pid, ws);
        } else {
            __syncthreads();                        // protect H from prior point's reads
            bn_to_H(acc0, wave, g, lcol, PAR0, ws, H);
            __syncthreads();

            // ---- layer 1 ----
            floatx4 acc1[2][2] = {};
#pragma unroll
            for (int ck = 0; ck < 4; ck++) {
                shortx8 B0 = *(const shortx8*)&H[lcol][ck * 32 + g * 8];
                shortx8 B1 = *(const shortx8*)&H[lcol + 16][ck * 32 + g * 8];
#pragma unroll
                for (int m = 0; m < 2; m++) {
                    shortx8 A = wf1[((wave * 2 + m) * 4 + ck) * 64 + lane];
                    acc1[m][0] = MFMA16(A, B0, acc1[m][0]);
                    acc1[m][1] = MFMA16(A, B1, acc1[m][1]);
                }
            }

            if constexpr (NL == 2) {
                store_stats128(acc1, wave, g, lcol, pid, ws);
            } else {
                __syncthreads();
                bn_to_H(acc1, wave, g, lcol, PAR1, ws, H);
                __syncthreads();

                // ---- layer 2 (256 out-ch: 4 M-tiles per wave) ----
                floatx4 acc2[4][2] = {};
#pragma unroll
                for (int ck = 0; ck < 4; ck++) {
                    shortx8 B0 = *(const shortx8*)&H[lcol][ck * 32 + g * 8];
                    shortx8 B1 = *(const shortx8*)&H[lcol + 16][ck * 32 + g * 8];
#pragma unroll
                    for (int m = 0; m < 4; m++) {
                        shortx8 A = wf2[((wave * 4 + m) * 4 + ck) * 64 + lane];
                        acc2[m][0] = MFMA16(A, B0, acc2[m][0]);
                        acc2[m][1] = MFMA16(A, B1, acc2[m][1]);
                    }
                }

                // stats (accumulate lane-local over p) + per-point max/min
#pragma unroll
                for (int m = 0; m < 4; m++) {
                    floatx4 mx, mn;
#pragma unroll
                    for (int r = 0; r < 4; r++) {
                        float a0 = acc2[m][0][r], a1 = acc2[m][1][r];
                        sv[m][r] += a0 + a1;
                        s2v[m][r] += a0 * a0 + a1 * a1;
                        mx[r] = fmaxf(a0, a1);
                        mn[r] = fminf(a0, a1);
                    }
#pragma unroll
                    for (int d = 1; d < 16; d <<= 1) {
#pragma unroll
                        for (int r = 0; r < 4; r++) {
                            mx[r] = fmaxf(mx[r], __shfl_xor(mx[r], d));
                            mn[r] = fminf(mn[r], __shfl_xor(mn[r], d));
                        }
                    }
                    if (lcol == 0) {
                        int ch = wave * 64 + m * 16 + g * 4;
                        *(floatx4*)&ws[MAXOFF + (size_t)pid * C2 + ch] = mx;
                        *(floatx4*)&ws[MINOFF + (size_t)pid * C2 + ch] = mn;
                    }
                }
            }
        }
    }

    if constexpr (NL == 3) {        // per-block stats row (accumulated over 2 points)
#pragma unroll
        for (int m = 0; m < 4; m++) {
            floatx4 s = sv[m], s2 = s2v[m];
#pragma unroll
            for (int r = 0; r < 4; r++) {
                float ss = s[r], qq = s2[r];
#pragma unroll
                for (int d = 1; d < 16; d <<= 1) { ss += __shfl_xor(ss, d); qq += __shfl_xor(qq, d); }
                s[r] = ss; s2[r] = qq;
            }
            if (lcol == 0) {
                int ch = wave * 64 + m * 16 + g * 4;
                *(floatx4*)&ws[PART3 + (size_t)bid * 512 + ch] = s;
                *(floatx4*)&ws[PART3 + (size_t)bid * 512 + 256 + ch] = s2;
            }
        }
    }
}

// level-1 reduction of partial rows (pitch 512): 64 blocks, coalesced
__global__ __launch_bounds__(256) void reduce1(float* __restrict__ ws, int srcoff,
                                               int rows_per_block, int ncol) {
    int j = blockIdx.x, t = threadIdx.x;
    const float* base = ws + srcoff + (size_t)j * rows_per_block * 512;
    float a0 = 0.f, a1 = 0.f;
    for (int i = 0; i < rows_per_block; i++) {
        a0 += base[(size_t)i * 512 + t];
        if (ncol > 256) a1 += base[(size_t)i * 512 + 256 + t];
    }
    ws[R1OFF + (size_t)j * 512 + t] = a0;
    if (ncol > 256) ws[R1OFF + (size_t)j * 512 + 256 + t] = a1;
}

__global__ void finalize(const float* __restrict__ g, const float* __restrict__ bparm,
                         float* __restrict__ ws, int CL, int paroff) {
    int ch = threadIdx.x;
    if (ch >= CL) return;
    float s = 0.f, s2 = 0.f;
    for (int j = 0; j < 64; j++) {
        s  += ws[R1OFF + (size_t)j * 512 + ch];
        s2 += ws[R1OFF + (size_t)j * 512 + CL + ch];
    }
    const float inv = 1.0f / ((float)BB * NN * KK);
    float mean = s * inv, var = s2 * inv - mean * mean;
    float sc = g[ch] * rsqrtf(var + EPSF);
    ws[paroff + ch] = sc;
    ws[paroff + CL + ch] = bparm[ch] - mean * sc;
}

// out = lrelu(scale*(scale>=0?max:min)+shift), transposed through LDS
__global__ __launch_bounds__(256) void out_kernel(const float* __restrict__ ws,
                                                  float* __restrict__ out) {
    __shared__ float T[32][261];
    int blk = blockIdx.x;                  // 256 blocks
    int b = blk >> 6, n0 = (blk & 63) * 32;
    int t = threadIdx.x;
    float s = ws[PAR2 + t], sh = ws[PAR2 + C2 + t];
    const float* Mx = ws + MAXOFF;
    const float* Mn = ws + MINOFF;
    for (int r = 0; r < 32; r++) {
        size_t base = ((size_t)(b * NN + n0 + r)) * C2 + t;
        float v = (s >= 0.f) ? Mx[base] : Mn[base];
        float z = fmaf(v, s, sh);
        T[r][t] = z >= 0.f ? z : SLOPE * z;
    }
    __syncthreads();
    float* o2 = out + BB * 3 * NN;
    int c = t & 31, og = t >> 5;
    for (int ss = 0; ss < 32; ss++) {
        int o = og * 32 + ss;
        o2[((size_t)(b * C2 + o)) * NN + n0 + c] = T[c][o];
    }
}

extern "C" void kernel_launch(void* const* d_in, const int* in_sizes, int n_in,
                              void* d_out, int out_size, void* d_ws, size_t ws_size,
                              hipStream_t stream) {
    const float* pos1 = (const float*)d_in[0];
    const float* pos2 = (const float*)d_in[1];
    const float* f1   = (const float*)d_in[2];
    const float* f2   = (const float*)d_in[3];
    const int*   idx  = (const int*)d_in[4];
    const float* W0 = (const float*)d_in[5];
    const float* g0 = (const float*)d_in[6];
    const float* b0 = (const float*)d_in[7];
    const float* W1 = (const float*)d_in[8];
    const float* g1 = (const float*)d_in[9];
    const float* b1 = (const float*)d_in[10];
    const float* W2 = (const float*)d_in[11];
    const float* g2 = (const float*)d_in[12];
    const float* b2 = (const float*)d_in[13];
    float* ws  = (float*)d_ws;
    float* out = (float*)d_out;
    ushort* wsu = (ushort*)d_ws;
    ushort* T2p = wsu + T2_USH;
    ushort* T1p = wsu + T1_USH;
    float* P1Tp = ws + P1TOFF;
    float* P2Tp = ws + P2TOFF;
    short* wp0  = (short*)(wsu + WP_USH);

    // output 0: pos1 passthrough
    hipMemcpyAsync(d_out, d_in[0], (size_t)BB * 3 * NN * sizeof(float),
                   hipMemcpyDeviceToDevice, stream);

    transpose_cn<<<BB * 64, 256, 0, stream>>>(f2, T2p);
    transpose_cn<<<BB * 64, 256, 0, stream>>>(f1, T1p);
    transpose_pos<<<32, 256, 0, stream>>>(pos1, pos2, P1Tp, P2Tp);
    pack_w<<<(NFRAG0 + NFRAG1 + NFRAG2) * 64 / 256, 256, 0, stream>>>(W0, W1, W2, wp0);

    pass_kernel<1><<<BB * NN / 2, 256, 0, stream>>>(T2p, T1p, P1Tp, P2Tp, idx, wp0, ws);
    reduce1<<<64, 256, 0, stream>>>(ws, MAXOFF, 128, 256);
    finalize<<<1, 256, 0, stream>>>(g0, b0, ws, C0, PAR0);

    pass_kernel<2><<<BB * NN / 2, 256, 0, stream>>>(T2p, T1p, P1Tp, P2Tp, idx, wp0, ws);
    reduce1<<<64, 256, 0, stream>>>(ws, MAXOFF, 128, 256);
    finalize<<<1, 256, 0, stream>>>(g1, b1, ws, C0, PAR1);

    pass_kernel<3><<<BB * NN / 2, 256, 0, stream>>>(T2p, T1p, P1Tp, P2Tp, idx, wp0, ws);
    reduce1<<<64, 256, 0, stream>>>(ws, PART3, 64, 512);
    finalize<<<1, 256, 0, stream>>>(g2, b2, ws, C2, PAR2);

    out_kernel<<<BB * (NN / 32), 256, 0, stream>>>(ws, out);
}

// Round 5
// 274.815 us; speedup vs baseline: 5.1737x; 1.5774x over previous
//
#include <hip/hip_runtime.h>
#include <cstdint>

#define BB 4
#define NN 2048
#define KK 32
#define CC 128
#define C0 128
#define C2 256
#define CIN0 259
#define RW 160                 // pre-transposed row width (128 feat | 3 pos | 29 zero)
#define EPSF 1e-5f
#define SLOPE 0.01f

// ---- ws layout (float offsets unless noted) ----
#define PAR0 0
#define PAR1 256
#define PAR2 512                          // -> 1024
#define R1OFF 1024                        // 64x512 -> 33792
#define MAXOFF 33792                      // 8192x256
#define MINOFF (MAXOFF + 2097152)
#define PART (MINOFF + 2097152)           // 2048x512 partial stats rows
#define T2_USH ((PART + 1048576) * 2)     // ushort offset; BB*NN*160 ush
#define T1_USH (T2_USH + BB*NN*RW)
#define WP_USH (T1_USH + BB*NN*RW)        // packed W: 176*512 ush

// packed-W frags: L0: 8 mt x 10 ck = 80; L1: 8x4=32; L2: 16x4=64
#define NFRAG0 80
#define NFRAG1 32
#define NFRAG2 64

typedef float floatx4 __attribute__((ext_vector_type(4)));
typedef short shortx8 __attribute__((ext_vector_type(8)));

#define MFMA16(A,B,C) __builtin_amdgcn_mfma_f32_16x16x32_bf16((A),(B),(C),0,0,0)

__device__ __forceinline__ ushort f2bf(float f) {
    union { float f; uint u; } v; v.f = f;
    uint r = (v.u + 0x7fffu + ((v.u >> 16) & 1u)) >> 16;
    return (ushort)r;
}

// feat[b][C][N] f32 + pos[b][3][N] f32 -> dst[b][n][160] bf16 rows:
// cols 0-127 feat, 128-130 sign*pos, 131-159 zero
__global__ __launch_bounds__(256) void transpose_fp(const float* __restrict__ feat,
                                                    const float* __restrict__ pos,
                                                    float sign, ushort* __restrict__ dst) {
    __shared__ __align__(16) ushort Ts[32][168];
    int b = blockIdx.x >> 6, n0 = (blockIdx.x & 63) * 32;
    int t = threadIdx.x;
#pragma unroll
    for (int i = 0; i < 16; i++) {
        int c = i * 8 + (t >> 5);
        Ts[t & 31][c] = f2bf(feat[((size_t)b * CC + c) * NN + n0 + (t & 31)]);
    }
    if (t < 96) {
        int c = t >> 5, k = t & 31;
        Ts[k][128 + c] = f2bf(sign * pos[((size_t)b * 3 + c) * NN + n0 + k]);
    }
    if (t < 32) {
        for (int c = 131; c < RW; c++) Ts[t][c] = 0;
    }
    __syncthreads();
    int n = t >> 3, q = t & 7;
    ushort* drow = dst + ((size_t)b * NN + n0 + n) * RW;
    // uint4 = 8 ushorts: two stores cover 16 cols (this was the round-4 bug)
    *(uint4*)&drow[q * 16]     = *(const uint4*)&Ts[n][q * 16];
    *(uint4*)&drow[q * 16 + 8] = *(const uint4*)&Ts[n][q * 16 + 8];
    if (q < 4) *(uint4*)&drow[128 + q * 8] = *(const uint4*)&Ts[n][128 + q * 8];
}

// Pack W into bf16 MFMA A-fragment order. L0 has 10 cin-chunks:
// ck 0-4 gather side: c<128 -> W0[o][3+c]; c 128-130 -> W0[o][c-128]; else 0
// ck 5-9 broadcast side: c<128 -> W0[o][131+c]; c 128-130 -> W0[o][c-128]; else 0
__global__ __launch_bounds__(256) void pack_w(const float* __restrict__ W0,
                                              const float* __restrict__ W1,
                                              const float* __restrict__ W2,
                                              short* __restrict__ wp0) {
    int tid = blockIdx.x * 256 + threadIdx.x;   // 176*64 = 11264
    int fid = tid >> 6, lane = tid & 63, g = (lane >> 4) & 3, lcol = lane & 15;
    short* wp1 = wp0 + NFRAG0 * 512;
    short* wp2 = wp1 + NFRAG1 * 512;
    ushort v[8];
    short* dst;
    if (fid < NFRAG0) {
        int mt = fid / 10, ck = fid % 10, o = mt * 16 + lcol;
        const float* wrow = W0 + (size_t)o * CIN0;
        int gather = (ck < 5);
        int cbase = (gather ? ck : ck - 5) * 32 + g * 8;
#pragma unroll
        for (int i = 0; i < 8; i++) {
            int c = cbase + i;
            float x;
            if (c < 128)      x = gather ? wrow[3 + c] : wrow[131 + c];
            else if (c < 131) x = wrow[c - 128];
            else              x = 0.f;
            v[i] = f2bf(x);
        }
        dst = wp0 + ((size_t)fid * 64 + lane) * 8;
    } else if (fid < NFRAG0 + NFRAG1) {
        int f = fid - NFRAG0, mt = f / 4, ck = f % 4, o = mt * 16 + lcol;
#pragma unroll
        for (int i = 0; i < 8; i++) v[i] = f2bf(W1[(size_t)o * C0 + ck * 32 + g * 8 + i]);
        dst = wp1 + ((size_t)f * 64 + lane) * 8;
    } else {
        int f = fid - NFRAG0 - NFRAG1, mt = f / 4, ck = f % 4, o = mt * 16 + lcol;
#pragma unroll
        for (int i = 0; i < 8; i++) v[i] = f2bf(W2[(size_t)o * C0 + ck * 32 + g * 8 + i]);
        dst = wp2 + ((size_t)f * 64 + lane) * 8;
    }
#pragma unroll
    for (int i = 0; i < 8; i++) dst[i] = (short)v[i];
}

// stats over all 4 points for a 128-ch layer -> one partial row per block
__device__ __forceinline__ void stats128_rows(const floatx4 (&acc)[4][2][2], int wave,
                                              int g, int lcol, int bid, float* ws) {
#pragma unroll
    for (int m = 0; m < 2; m++) {
        floatx4 s = {}, q = {};
#pragma unroll
        for (int p = 0; p < 4; p++)
#pragma unroll
            for (int r = 0; r < 4; r++) {
                float a0 = acc[p][m][0][r], a1 = acc[p][m][1][r];
                s[r] += a0 + a1; q[r] += a0 * a0 + a1 * a1;
            }
#pragma unroll
        for (int r = 0; r < 4; r++) {
            float ss = s[r], qq = q[r];
#pragma unroll
            for (int d = 1; d < 16; d <<= 1) { ss += __shfl_xor(ss, d); qq += __shfl_xor(qq, d); }
            s[r] = ss; q[r] = qq;
        }
        if (lcol == 0) {
            int ch = wave * 32 + m * 16 + g * 4;
            *(floatx4*)&ws[PART + (size_t)bid * 512 + ch] = s;
            *(floatx4*)&ws[PART + (size_t)bid * 512 + 128 + ch] = q;
        }
    }
}

// BN+lrelu -> bf16 into H[p][k][ch]
__device__ __forceinline__ void bn_to_H4(const floatx4 (&acc)[4][2][2], int wave, int g,
                                         int lcol, int paroff, const float* __restrict__ ws,
                                         ushort (*H)[32][136]) {
#pragma unroll
    for (int m = 0; m < 2; m++) {
        int ch = wave * 32 + m * 16 + g * 4;
        floatx4 sc = *(const floatx4*)&ws[paroff + ch];
        floatx4 sh = *(const floatx4*)&ws[paroff + 128 + ch];
#pragma unroll
        for (int p = 0; p < 4; p++)
#pragma unroll
            for (int nt = 0; nt < 2; nt++) {
                ushort h[4];
#pragma unroll
                for (int r = 0; r < 4; r++) {
                    float z = fmaf(acc[p][m][nt][r], sc[r], sh[r]);
                    z = z >= 0.f ? z : SLOPE * z;
                    h[r] = f2bf(z);
                }
                uint2 val;
                val.x = (uint)h[0] | ((uint)h[1] << 16);
                val.y = (uint)h[2] | ((uint)h[3] << 16);
                *(uint2*)&H[p][nt * 16 + lcol][ch] = val;
            }
    }
}

// One block = 4 points; 4 waves split M; A-frags amortized over 4 points.
template<int NL>
__global__ __launch_bounds__(256, 2) void pass_kernel(
    const ushort* __restrict__ T2x, const ushort* __restrict__ T1x,
    const int* __restrict__ idxg, const short* __restrict__ wp0,
    float* __restrict__ ws)
{
    const int bid = blockIdx.x;
    const int t = threadIdx.x;
    const int wave = t >> 6, lane = t & 63, g = (lane >> 4) & 3, lcol = lane & 15;
    const int pid0 = bid * 4;
    const int b = pid0 >> 11;
    const shortx8* wf0 = (const shortx8*)wp0;
    const shortx8* wf1 = wf0 + NFRAG0 * 64;
    const shortx8* wf2 = wf1 + NFRAG1 * 64;

    const ushort* r0[4]; const ushort* r1[4]; const ushort* fr[4];
#pragma unroll
    for (int p = 0; p < 4; p++) {
        int pid = pid0 + p;
        int n = pid & (NN - 1);
        int j0 = idxg[pid * KK + lcol];
        int j1 = idxg[pid * KK + 16 + lcol];
        r0[p] = T2x + ((size_t)(b * NN + j0)) * RW;
        r1[p] = T2x + ((size_t)(b * NN + j1)) * RW;
        fr[p] = T1x + ((size_t)(b * NN + n)) * RW;
    }

    // ---- layer 0 ----
    floatx4 acc[4][2][2] = {};
#pragma unroll
    for (int ck = 0; ck < 5; ck++) {           // gather chunks
        shortx8 B0[4], B1[4];
#pragma unroll
        for (int p = 0; p < 4; p++) {
            B0[p] = *(const shortx8*)(r0[p] + ck * 32 + g * 8);
            B1[p] = *(const shortx8*)(r1[p] + ck * 32 + g * 8);
        }
#pragma unroll
        for (int m = 0; m < 2; m++) {
            shortx8 A = wf0[((wave * 2 + m) * 10 + ck) * 64 + lane];
#pragma unroll
            for (int p = 0; p < 4; p++) {
                acc[p][m][0] = MFMA16(A, B0[p], acc[p][m][0]);
                acc[p][m][1] = MFMA16(A, B1[p], acc[p][m][1]);
            }
        }
    }
#pragma unroll
    for (int ck = 0; ck < 5; ck++) {           // broadcast chunks (f1 | -pos1)
        shortx8 F[4];
#pragma unroll
        for (int p = 0; p < 4; p++)
            F[p] = *(const shortx8*)(fr[p] + ck * 32 + g * 8);
#pragma unroll
        for (int m = 0; m < 2; m++) {
            shortx8 A = wf0[((wave * 2 + m) * 10 + 5 + ck) * 64 + lane];
#pragma unroll
            for (int p = 0; p < 4; p++) {
                acc[p][m][0] = MFMA16(A, F[p], acc[p][m][0]);
                acc[p][m][1] = MFMA16(A, F[p], acc[p][m][1]);
            }
        }
    }

    if constexpr (NL == 1) {
        stats128_rows(acc, wave, g, lcol, bid, ws);
    } else {
        __shared__ __align__(16) ushort H[4][32][136];
        bn_to_H4(acc, wave, g, lcol, PAR0, ws, H);
        __syncthreads();

        // ---- layer 1 ----
        floatx4 acc1[4][2][2] = {};
#pragma unroll
        for (int ck = 0; ck < 4; ck++) {
            shortx8 B0[4], B1[4];
#pragma unroll
            for (int p = 0; p < 4; p++) {
                B0[p] = *(const shortx8*)&H[p][lcol][ck * 32 + g * 8];
                B1[p] = *(const shortx8*)&H[p][lcol + 16][ck * 32 + g * 8];
            }
#pragma unroll
            for (int m = 0; m < 2; m++) {
                shortx8 A = wf1[((wave * 2 + m) * 4 + ck) * 64 + lane];
#pragma unroll
                for (int p = 0; p < 4; p++) {
                    acc1[p][m][0] = MFMA16(A, B0[p], acc1[p][m][0]);
                    acc1[p][m][1] = MFMA16(A, B1[p], acc1[p][m][1]);
                }
            }
        }

        if constexpr (NL == 2) {
            stats128_rows(acc1, wave, g, lcol, bid, ws);
        } else {
            __syncthreads();                   // all L1 reads of H done
            bn_to_H4(acc1, wave, g, lcol, PAR1, ws, H);
            __syncthreads();

            // ---- layer 2: two M-halves (M=32/wave each) ----
#pragma unroll
            for (int mh = 0; mh < 2; mh++) {
                floatx4 acc2[4][2][2] = {};
#pragma unroll
                for (int ck = 0; ck < 4; ck++) {
                    shortx8 B0[4], B1[4];
#pragma unroll
                    for (int p = 0; p < 4; p++) {
                        B0[p] = *(const shortx8*)&H[p][lcol][ck * 32 + g * 8];
                        B1[p] = *(const shortx8*)&H[p][lcol + 16][ck * 32 + g * 8];
                    }
#pragma unroll
                    for (int m = 0; m < 2; m++) {
                        int mt = wave * 4 + mh * 2 + m;
                        shortx8 A = wf2[(mt * 4 + ck) * 64 + lane];
#pragma unroll
                        for (int p = 0; p < 4; p++) {
                            acc2[p][m][0] = MFMA16(A, B0[p], acc2[p][m][0]);
                            acc2[p][m][1] = MFMA16(A, B1[p], acc2[p][m][1]);
                        }
                    }
                }
                // stats + per-point max/min
#pragma unroll
                for (int m = 0; m < 2; m++) {
                    int ch = (wave * 4 + mh * 2 + m) * 16 + g * 4;
                    floatx4 s = {}, q = {};
#pragma unroll
                    for (int p = 0; p < 4; p++)
#pragma unroll
                        for (int r = 0; r < 4; r++) {
                            float a0 = acc2[p][m][0][r], a1 = acc2[p][m][1][r];
                            s[r] += a0 + a1; q[r] += a0 * a0 + a1 * a1;
                        }
#pragma unroll
                    for (int r = 0; r < 4; r++) {
                        float ss = s[r], qq = q[r];
#pragma unroll
                        for (int d = 1; d < 16; d <<= 1) { ss += __shfl_xor(ss, d); qq += __shfl_xor(qq, d); }
                        s[r] = ss; q[r] = qq;
                    }
                    if (lcol == 0) {
                        *(floatx4*)&ws[PART + (size_t)bid * 512 + ch] = s;
                        *(floatx4*)&ws[PART + (size_t)bid * 512 + 256 + ch] = q;
                    }
#pragma unroll
                    for (int p = 0; p < 4; p++) {
                        floatx4 mx, mn;
#pragma unroll
                        for (int r = 0; r < 4; r++) {
                            mx[r] = fmaxf(acc2[p][m][0][r], acc2[p][m][1][r]);
                            mn[r] = fminf(acc2[p][m][0][r], acc2[p][m][1][r]);
                        }
#pragma unroll
                        for (int d = 1; d < 16; d <<= 1) {
#pragma unroll
                            for (int r = 0; r < 4; r++) {
                                mx[r] = fmaxf(mx[r], __shfl_xor(mx[r], d));
                                mn[r] = fminf(mn[r], __shfl_xor(mn[r], d));
                            }
                        }
                        if (lcol == 0) {
                            *(floatx4*)&ws[MAXOFF + (size_t)(pid0 + p) * C2 + ch] = mx;
                            *(floatx4*)&ws[MINOFF + (size_t)(pid0 + p) * C2 + ch] = mn;
                        }
                    }
                }
            }
        }
    }
}

// level-1 reduction: 2048 partial rows (pitch 512) -> 64 rows
__global__ __launch_bounds__(256) void reduce1(float* __restrict__ ws, int srcoff,
                                               int rows_per_block, int ncol) {
    int j = blockIdx.x, t = threadIdx.x;
    const float* base = ws + srcoff + (size_t)j * rows_per_block * 512;
    float a0 = 0.f, a1 = 0.f;
    for (int i = 0; i < rows_per_block; i++) {
        a0 += base[(size_t)i * 512 + t];
        if (ncol > 256) a1 += base[(size_t)i * 512 + 256 + t];
    }
    ws[R1OFF + (size_t)j * 512 + t] = a0;
    if (ncol > 256) ws[R1OFF + (size_t)j * 512 + 256 + t] = a1;
}

__global__ void finalize(const float* __restrict__ g, const float* __restrict__ bparm,
                         float* __restrict__ ws, int CL, int paroff) {
    int ch = threadIdx.x;
    if (ch >= CL) return;
    float s = 0.f, s2 = 0.f;
    for (int j = 0; j < 64; j++) {
        s  += ws[R1OFF + (size_t)j * 512 + ch];
        s2 += ws[R1OFF + (size_t)j * 512 + CL + ch];
    }
    const float inv = 1.0f / ((float)BB * NN * KK);
    float mean = s * inv, var = s2 * inv - mean * mean;
    float sc = g[ch] * rsqrtf(var + EPSF);
    ws[paroff + ch] = sc;
    ws[paroff + CL + ch] = bparm[ch] - mean * sc;
}

// out = lrelu(scale*(scale>=0?max:min)+shift), transposed through LDS
__global__ __launch_bounds__(256) void out_kernel(const float* __restrict__ ws,
                                                  float* __restrict__ out) {
    __shared__ float T[32][261];
    int blk = blockIdx.x;                  // 256 blocks
    int b = blk >> 6, n0 = (blk & 63) * 32;
    int t = threadIdx.x;
    float s = ws[PAR2 + t], sh = ws[PAR2 + C2 + t];
    const float* Mx = ws + MAXOFF;
    const float* Mn = ws + MINOFF;
    for (int r = 0; r < 32; r++) {
        size_t base = ((size_t)(b * NN + n0 + r)) * C2 + t;
        float v = (s >= 0.f) ? Mx[base] : Mn[base];
        float z = fmaf(v, s, sh);
        T[r][t] = z >= 0.f ? z : SLOPE * z;
    }
    __syncthreads();
    float* o2 = out + BB * 3 * NN;
    int c = t & 31, og = t >> 5;
    for (int ss = 0; ss < 32; ss++) {
        int o = og * 32 + ss;
        o2[((size_t)(b * C2 + o)) * NN + n0 + c] = T[c][o];
    }
}

extern "C" void kernel_launch(void* const* d_in, const int* in_sizes, int n_in,
                              void* d_out, int out_size, void* d_ws, size_t ws_size,
                              hipStream_t stream) {
    const float* pos1 = (const float*)d_in[0];
    const float* pos2 = (const float*)d_in[1];
    const float* f1   = (const float*)d_in[2];
    const float* f2   = (const float*)d_in[3];
    const int*   idx  = (const int*)d_in[4];
    const float* W0 = (const float*)d_in[5];
    const float* g0 = (const float*)d_in[6];
    const float* b0 = (const float*)d_in[7];
    const float* W1 = (const float*)d_in[8];
    const float* g1 = (const float*)d_in[9];
    const float* b1 = (const float*)d_in[10];
    const float* W2 = (const float*)d_in[11];
    const float* g2 = (const float*)d_in[12];
    const float* b2 = (const float*)d_in[13];
    float* ws  = (float*)d_ws;
    float* out = (float*)d_out;
    ushort* wsu = (ushort*)d_ws;
    ushort* T2p = wsu + T2_USH;
    ushort* T1p = wsu + T1_USH;
    short* wp0  = (short*)(wsu + WP_USH);

    // output 0: pos1 passthrough
    hipMemcpyAsync(d_out, d_in[0], (size_t)BB * 3 * NN * sizeof(float),
                   hipMemcpyDeviceToDevice, stream);

    transpose_fp<<<BB * 64, 256, 0, stream>>>(f2, pos2,  1.0f, T2p);
    transpose_fp<<<BB * 64, 256, 0, stream>>>(f1, pos1, -1.0f, T1p);
    pack_w<<<(NFRAG0 + NFRAG1 + NFRAG2) * 64 / 256, 256, 0, stream>>>(W0, W1, W2, wp0);

    pass_kernel<1><<<BB * NN / 4, 256, 0, stream>>>(T2p, T1p, idx, wp0, ws);
    reduce1<<<64, 256, 0, stream>>>(ws, PART, 32, 256);
    finalize<<<1, 256, 0, stream>>>(g0, b0, ws, C0, PAR0);

    pass_kernel<2><<<BB * NN / 4, 256, 0, stream>>>(T2p, T1p, idx, wp0, ws);
    reduce1<<<64, 256, 0, stream>>>(ws, PART, 32, 256);
    finalize<<<1, 256, 0, stream>>>(g1, b1, ws, C0, PAR1);

    pass_kernel<3><<<BB * NN / 4, 256, 0, stream>>>(T2p, T1p, idx, wp0, ws);
    reduce1<<<64, 256, 0, stream>>>(ws, PART, 32, 512);
    finalize<<<1, 256, 0, stream>>>(g2, b2, ws, C2, PAR2);

    out_kernel<<<BB * (NN / 32), 256, 0, stream>>>(ws, out);
}